// Round 3
// baseline (1718.931 us; speedup 1.0000x reference)
//
#include <hip/hip_runtime.h>

typedef _Float16 half8 __attribute__((ext_vector_type(8)));
typedef _Float16 half4v __attribute__((ext_vector_type(4)));
typedef _Float16 half2v __attribute__((ext_vector_type(2)));
typedef float f32x4 __attribute__((ext_vector_type(4)));

__device__ __forceinline__ void gload16(const _Float16* g, _Float16* l) {
  __builtin_amdgcn_global_load_lds((const __attribute__((address_space(1))) void*)g,
                                   (__attribute__((address_space(3))) void*)l, 16, 0, 0);
}

// ---------------------------------------------------------------------------
__global__ __launch_bounds__(256) void cast_k(const float* __restrict__ in,
                                              _Float16* __restrict__ out, int n) {
  int i = (blockIdx.x * 256 + threadIdx.x) << 2;
  if (i < n) {
    float4 v = *(const float4*)(in + i);
    half4v h;
    h[0] = (_Float16)v.x; h[1] = (_Float16)v.y; h[2] = (_Float16)v.z; h[3] = (_Float16)v.w;
    *(half4v*)(out + i) = h;
  }
}

// ---------------------------------------------------------------------------
// W[K][N] fp32 -> WT[N][K] fp16 (one 32x32 tile per block)
__device__ __forceinline__ void tcast_core(const float* __restrict__ W,
                                           _Float16* __restrict__ WT, int K, int N,
                                           int n0, int k0, float tile[32][33]) {
  const int tx = threadIdx.x & 31, ty = threadIdx.x >> 5;  // 32 x 8
#pragma unroll
  for (int i = 0; i < 4; i++)
    tile[ty + i * 8][tx] = W[(size_t)(k0 + ty + i * 8) * N + n0 + tx];
  __syncthreads();
#pragma unroll
  for (int i = 0; i < 4; i++)
    WT[(size_t)(n0 + ty + i * 8) * K + k0 + tx] = (_Float16)tile[tx][ty + i * 8];
}

__global__ __launch_bounds__(256) void tcast_k(const float* __restrict__ W,
                                               _Float16* __restrict__ WT, int K, int N) {
  __shared__ float tile[32][33];
  tcast_core(W, WT, K, N, blockIdx.x << 5, blockIdx.y << 5, tile);
}

// all per-layer weights in one launch: enc(1536) res1(2048) res2(2048) out(32)
__global__ __launch_bounds__(256) void tcast_all(const float* __restrict__ enc_w, _Float16* encT,
                                                 const float* __restrict__ res_w1, _Float16* res1T,
                                                 const float* __restrict__ res_w2, _Float16* res2T,
                                                 const float* __restrict__ out_w, _Float16* outT) {
  __shared__ float tile[32][33];
  int bid = blockIdx.x;
  if (bid < 1536) {  // enc: K=256 N=768, 24x8 per z
    const int z = bid / 192, r = bid % 192;
    tcast_core(enc_w + (size_t)z * 196608, encT + (size_t)z * 196608, 256, 768,
               (r % 24) << 5, (r / 24) << 5, tile);
  } else if (bid < 3584) {  // res1: K=256 N=1024, 32x8 per z
    bid -= 1536;
    const int z = bid / 256, r = bid % 256;
    tcast_core(res_w1 + (size_t)z * 262144, res1T + (size_t)z * 262144, 256, 1024,
               (r % 32) << 5, (r / 32) << 5, tile);
  } else if (bid < 5632) {  // res2: K=1024 N=256, 8x32 per z
    bid -= 3584;
    const int z = bid / 256, r = bid % 256;
    tcast_core(res_w2 + (size_t)z * 262144, res2T + (size_t)z * 262144, 1024, 256,
               (r % 8) << 5, (r / 8) << 5, tile);
  } else {  // out: K=256 N=128, 4x8
    bid -= 5632;
    tcast_core(out_w, outT, 256, 128, (bid % 4) << 5, (bid / 4) << 5, tile);
  }
}

// ---------------------------------------------------------------------------
// NT GEMM: C[M,N] = epilogue(A[M,K] @ Bt[N,K]^T + bias), XOR-swizzled LDS, BK templated.
// MODE: 0 relu->H | 1 tanh->H | 2 bias->H | 3 +pos->F | 4 gelu->H | 5 +aux->F&H | 7 ->F+stats
template <int BM, int BN, int BK, int WGM, int WGN, int MODE>
__global__ __launch_bounds__(256) void gemm_nt(const _Float16* __restrict__ A,
                                               const _Float16* __restrict__ Bt,
                                               const float* __restrict__ bias,
                                               _Float16* __restrict__ outH,
                                               float* __restrict__ outF,
                                               const float* __restrict__ aux,
                                               float* __restrict__ stats,
                                               int M, int N, int K) {
  constexpr int CPR = BK / 8;
  constexpr int TM = BM / WGM, TN = BN / WGN;
  constexpr int AM = TM / 16, AN = TN / 16;
  constexpr int LA = BM * BK / 2048, LB = BN * BK / 2048;
  __shared__ __align__(16) _Float16 As[BM * BK];
  __shared__ __align__(16) _Float16 Bs[BN * BK];
  const int tid = threadIdx.x;
  const int lane = tid & 63, w = tid >> 6;
  const int wr = (w / WGN) * TM, wc = (w % WGN) * TN;
  const int lr = lane & 15, quad = lane >> 4;
  const int mb = blockIdx.y * BM, nb = blockIdx.x * BN;

  const _Float16* ga[LA];
  const _Float16* gb[LB];
  _Float16* la[LA];
  _Float16* lb[LB];
#pragma unroll
  for (int i = 0; i < LA; i++) {
    const int c = tid + i * 256, row = c / CPR, j = c % CPR;
    ga[i] = A + (size_t)(mb + row) * K + ((j ^ (row & 7)) << 3);
    la[i] = As + c * 8;
  }
#pragma unroll
  for (int i = 0; i < LB; i++) {
    const int c = tid + i * 256, row = c / CPR, j = c % CPR;
    gb[i] = Bt + (size_t)(nb + row) * K + ((j ^ (row & 7)) << 3);
    lb[i] = Bs + c * 8;
  }

  f32x4 acc[AM][AN] = {};

  for (int k0 = 0; k0 < K; k0 += BK) {
#pragma unroll
    for (int i = 0; i < LA; i++) gload16(ga[i] + k0, la[i]);
#pragma unroll
    for (int i = 0; i < LB; i++) gload16(gb[i] + k0, lb[i]);
    __syncthreads();
#pragma unroll
    for (int ks = 0; ks < BK / 32; ks++) {
      const int pc = (((ks << 2) | quad) ^ (lane & 7)) << 3;
      half8 af[AM], bf[AN];
#pragma unroll
      for (int mt = 0; mt < AM; mt++)
        af[mt] = *(const half8*)(As + (wr + mt * 16 + lr) * BK + pc);
#pragma unroll
      for (int nt = 0; nt < AN; nt++)
        bf[nt] = *(const half8*)(Bs + (wc + nt * 16 + lr) * BK + pc);
#pragma unroll
      for (int mt = 0; mt < AM; mt++)
#pragma unroll
        for (int nt = 0; nt < AN; nt++)
          acc[mt][nt] = __builtin_amdgcn_mfma_f32_16x16x32_f16(af[mt], bf[nt], acc[mt][nt], 0, 0, 0);
    }
    __syncthreads();
  }

  float ls = 0.0f, lsq = 0.0f;
#pragma unroll
  for (int nt = 0; nt < AN; nt++) {
    const int col = nb + wc + (nt << 4) + lr;
    const float bv = bias[col];
#pragma unroll
    for (int mt = 0; mt < AM; mt++) {
      const int row0 = mb + wr + (mt << 4) + (quad << 2);
#pragma unroll
      for (int r = 0; r < 4; r++) {
        const int row = row0 + r;
        const size_t off = (size_t)row * N + col;
        float v = acc[mt][nt][r] + bv;
        if (MODE == 0) {
          outH[off] = (_Float16)fmaxf(v, 0.0f);
        } else if (MODE == 1) {
          outH[off] = (_Float16)tanhf(v);
        } else if (MODE == 2) {
          outH[off] = (_Float16)v;
        } else if (MODE == 3) {
          outF[off] = v + aux[(size_t)(row & 511) * N + col];  // + pos_w[s]
        } else if (MODE == 4) {
          outH[off] = (_Float16)(0.5f * v * (1.0f + erff(v * 0.70710678118654752f)));
        } else if (MODE == 5) {
          float xv = aux[off] + v;  // residual add
          outF[off] = xv;
          outH[off] = (_Float16)xv;
        } else {
          outF[off] = v;
          if (MODE == 7) { ls += v; lsq += v * v; }
        }
      }
    }
  }
  if (MODE == 7) {
#pragma unroll
    for (int o = 32; o; o >>= 1) { ls += __shfl_xor(ls, o); lsq += __shfl_xor(lsq, o); }
    if (lane == 0) {
      atomicAdd(&stats[0], ls);
      atomicAdd(&stats[1], lsq);
    }
  }
}

// ---------------------------------------------------------------------------
// Fused LN + single-shot GEMM: out = epi(LN(X [+ Aadd]) @ Bt + bias).
// BM=64, K=BK=256 fixed, BN=64. If ADD: block bx==0 also stores LN'd rows fp32 to xout.
// MODE: 2 bias->H | 4 gelu->H
template <int MODE, bool ADD>
__global__ __launch_bounds__(256) void gemm_ln(const float* __restrict__ X,
                                               const float* __restrict__ Aadd,
                                               const float* __restrict__ lng,
                                               const float* __restrict__ lnb,
                                               const _Float16* __restrict__ Bt,
                                               const float* __restrict__ bias,
                                               _Float16* __restrict__ outH,
                                               float* __restrict__ xout, int N) {
  __shared__ __align__(16) _Float16 As[64 * 256];
  __shared__ __align__(16) _Float16 Bs[64 * 256];
  const int tid = threadIdx.x;
  const int lane = tid & 63, w = tid >> 6;
  const int wr = (w >> 1) << 5, wc = (w & 1) << 5;
  const int lr = lane & 15, quad = lane >> 4;
  const int mb = blockIdx.y << 6, nb = blockIdx.x << 6;

  // B staging: async direct-to-LDS, swizzled
#pragma unroll
  for (int i = 0; i < 8; i++) {
    const int c = tid + i * 256, row = c >> 5, j = c & 31;
    gload16(Bt + (size_t)(nb + row) * 256 + ((j ^ (row & 7)) << 3), Bs + c * 8);
  }

  // A staging: load fp32 row quarter, LN in registers, ds_write fp16 swizzled
  const int r = tid >> 2, qq = tid & 3;
  float vals[64];
  {
    const float4* xp = (const float4*)(X + ((size_t)(mb + r) << 8) + (qq << 6));
    const float4* ap = (const float4*)(Aadd + ((size_t)(mb + r) << 8) + (qq << 6));
    float s = 0.0f, sq = 0.0f;
#pragma unroll
    for (int i = 0; i < 16; i++) {
      float4 v = xp[i];
      if (ADD) {
        float4 a = ap[i];
        v.x += a.x; v.y += a.y; v.z += a.z; v.w += a.w;
      }
      vals[i * 4 + 0] = v.x; vals[i * 4 + 1] = v.y; vals[i * 4 + 2] = v.z; vals[i * 4 + 3] = v.w;
      s += v.x + v.y + v.z + v.w;
      sq += v.x * v.x + v.y * v.y + v.z * v.z + v.w * v.w;
    }
    s += __shfl_xor(s, 1); s += __shfl_xor(s, 2);
    sq += __shfl_xor(sq, 1); sq += __shfl_xor(sq, 2);
    const float mean = s * 0.00390625f;
    const float rs = rsqrtf(sq * 0.00390625f - mean * mean + 1e-5f);
    const float4* g4 = (const float4*)(lng + (qq << 6));
    const float4* b4 = (const float4*)(lnb + (qq << 6));
#pragma unroll
    for (int i = 0; i < 16; i++) {
      float4 g = g4[i], b = b4[i];
      vals[i * 4 + 0] = (vals[i * 4 + 0] - mean) * rs * g.x + b.x;
      vals[i * 4 + 1] = (vals[i * 4 + 1] - mean) * rs * g.y + b.y;
      vals[i * 4 + 2] = (vals[i * 4 + 2] - mean) * rs * g.z + b.z;
      vals[i * 4 + 3] = (vals[i * 4 + 3] - mean) * rs * g.w + b.w;
    }
#pragma unroll
    for (int cc = 0; cc < 8; cc++) {
      half8 h;
#pragma unroll
      for (int j = 0; j < 8; j++) h[j] = (_Float16)vals[cc * 8 + j];
      *(half8*)(As + r * 256 + ((((qq << 3) | cc) ^ (r & 7)) << 3)) = h;
    }
    if (ADD && blockIdx.x == 0) {
      float4* xo = (float4*)(xout + ((size_t)(mb + r) << 8) + (qq << 6));
#pragma unroll
      for (int i = 0; i < 16; i++) {
        float4 o;
        o.x = vals[i * 4 + 0]; o.y = vals[i * 4 + 1]; o.z = vals[i * 4 + 2]; o.w = vals[i * 4 + 3];
        xo[i] = o;
      }
    }
  }
  __syncthreads();

  f32x4 acc[2][2] = {};
#pragma unroll
  for (int ks = 0; ks < 8; ks++) {
    const int pc = (((ks << 2) | quad) ^ (lane & 7)) << 3;
    half8 af[2], bf[2];
#pragma unroll
    for (int mt = 0; mt < 2; mt++) af[mt] = *(const half8*)(As + (wr + mt * 16 + lr) * 256 + pc);
#pragma unroll
    for (int nt = 0; nt < 2; nt++) bf[nt] = *(const half8*)(Bs + (wc + nt * 16 + lr) * 256 + pc);
#pragma unroll
    for (int mt = 0; mt < 2; mt++)
#pragma unroll
      for (int nt = 0; nt < 2; nt++)
        acc[mt][nt] = __builtin_amdgcn_mfma_f32_16x16x32_f16(af[mt], bf[nt], acc[mt][nt], 0, 0, 0);
  }

#pragma unroll
  for (int nt = 0; nt < 2; nt++) {
    const int col = nb + wc + (nt << 4) + lr;
    const float bv = bias[col];
#pragma unroll
    for (int mt = 0; mt < 2; mt++) {
      const int row0 = mb + wr + (mt << 4) + (quad << 2);
#pragma unroll
      for (int rr = 0; rr < 4; rr++) {
        const size_t off = (size_t)(row0 + rr) * N + col;
        float v = acc[mt][nt][rr] + bv;
        if (MODE == 4)
          outH[off] = (_Float16)(0.5f * v * (1.0f + erff(v * 0.70710678118654752f)));
        else
          outH[off] = (_Float16)v;
      }
    }
  }
}

// ---------------------------------------------------------------------------
// Causal flash attention. Block = (b, h, 64-row q-tile); 512 blocks.
__global__ __launch_bounds__(256) void attn_k(const _Float16* __restrict__ qkv,
                                              float* __restrict__ aout) {
  __shared__ __align__(16) char smem[65536];
  _Float16* Ks = (_Float16*)smem;
  _Float16* Vs = (_Float16*)(smem + 32768);
  float* Om = (float*)smem;
  float* Ol = (float*)(smem + 768);
  float* Os = (float*)(smem + 1536);

  const int bid = blockIdx.x;
  const int qt = 7 - (bid & 7), h = (bid >> 3) & 7, b = bid >> 6;
  const int q0 = qt << 6;
  const int t = threadIdx.x, p = t >> 6, tr = t & 63, q = q0 + tr;
  const int nkt = qt + 1;
  const size_t rowbase = (size_t)(b * 512) * 768;

  const half2v* q2 = (const half2v*)(qkv + rowbase + (size_t)q * 768 + h * 32);
  half2v qh[16];
#pragma unroll
  for (int i = 0; i < 16; i++) qh[i] = q2[i];

  for (int c = t; c < nkt * 256; c += 256) {
    const int row = c >> 2, off = (c & 3) << 3;
    const _Float16* kp = qkv + rowbase + (size_t)row * 768 + 256 + h * 32 + off;
    gload16(kp, Ks + c * 8);
    gload16(kp + 256, Vs + c * 8);
  }
  __syncthreads();

  float O[32];
#pragma unroll
  for (int d = 0; d < 32; d++) O[d] = 0.0f;
  float m = -1e30f, lsum = 0.0f;

  for (int kt = p; kt < nkt; kt += 4) {
    const int kb = kt << 6;
    const int rows = (kt == qt) ? (tr + 1) : 64;
    for (int j0 = 0; j0 < rows; j0 += 8) {
      float s[8];
      float mx = -1e30f;
#pragma unroll
      for (int jj = 0; jj < 8; jj++) {
        const half2v* kr = (const half2v*)(Ks + (size_t)(kb + j0 + jj) * 32);
        float a0 = 0.0f, a1 = 0.0f;
#pragma unroll
        for (int d = 0; d < 8; d++) {
          a0 = __builtin_amdgcn_fdot2(qh[d], kr[d], a0, false);
          a1 = __builtin_amdgcn_fdot2(qh[d + 8], kr[d + 8], a1, false);
        }
        const float sc = (a0 + a1) * 0.17677669529663687f;
        s[jj] = (kb + j0 + jj <= q) ? sc : -1e30f;
        mx = fmaxf(mx, s[jj]);
      }
      const float mn = fmaxf(m, mx);
      const float corr = __expf(m - mn);
      lsum *= corr;
#pragma unroll
      for (int d = 0; d < 32; d++) O[d] *= corr;
      m = mn;
#pragma unroll
      for (int jj = 0; jj < 8; jj++) {
        const float pw = __expf(s[jj] - m);
        lsum += pw;
        const half8* vr = (const half8*)(Vs + (size_t)(kb + j0 + jj) * 32);
#pragma unroll
        for (int i = 0; i < 4; i++) {
          half8 vv = vr[i];
#pragma unroll
          for (int d = 0; d < 8; d++) O[i * 8 + d] = fmaf(pw, (float)vv[d], O[i * 8 + d]);
        }
      }
    }
  }

  __syncthreads();
  if (p > 0) {
    Om[(p - 1) * 64 + tr] = m;
    Ol[(p - 1) * 64 + tr] = lsum;
    float* od = Os + ((p - 1) * 64 + tr) * 33;
#pragma unroll
    for (int d = 0; d < 32; d++) od[d] = O[d];
  }
  __syncthreads();
  if (p == 0) {
    float mn = m;
#pragma unroll
    for (int pp = 0; pp < 3; pp++) mn = fmaxf(mn, Om[pp * 64 + tr]);
    const float c0 = __expf(m - mn);
    float lt = lsum * c0;
    float cs[3];
#pragma unroll
    for (int pp = 0; pp < 3; pp++) {
      cs[pp] = __expf(Om[pp * 64 + tr] - mn);
      lt += Ol[pp * 64 + tr] * cs[pp];
    }
    const float inv = 1.0f / lt;
    float* op = aout + ((size_t)(b * 512 + q)) * 256 + h * 32;
#pragma unroll
    for (int d = 0; d < 32; d++) {
      float v = O[d] * c0;
#pragma unroll
      for (int pp = 0; pp < 3; pp++) v += Os[(pp * 64 + tr) * 33 + d] * cs[pp];
      op[d] = v * inv;
    }
  }
}

// ---------------------------------------------------------------------------
__global__ __launch_bounds__(256) void finalize_k(const float4* __restrict__ enc,
                                                  const float* __restrict__ stats,
                                                  float4* __restrict__ out, int n4, float n) {
  const int i = blockIdx.x * 256 + threadIdx.x;
  if (i >= n4) return;
  const float s = stats[0], q = stats[1];
  const float mean = s / n;
  const float var = (q - s * s / n) / (n - 1.0f);  // ddof=1
  const float inv = rsqrtf(var);
  float4 x = enc[i];
  float4 o;
  o.x = (x.x - mean) * inv + 1e-10f;
  o.y = (x.y - mean) * inv + 1e-10f;
  o.z = (x.z - mean) * inv + 1e-10f;
  o.w = (x.w - mean) * inv + 1e-10f;
  out[i] = o;
}

// ---------------------------------------------------------------------------
extern "C" void kernel_launch(void* const* d_in, const int* in_sizes, int n_in,
                              void* d_out, int out_size, void* d_ws, size_t ws_size,
                              hipStream_t stream) {
  const float* state = (const float*)d_in[0];
  const float* fc1_w = (const float*)d_in[1];
  const float* fc1_b = (const float*)d_in[2];
  const float* fc2_w = (const float*)d_in[3];
  const float* fc2_b = (const float*)d_in[4];
  const float* fc3_w = (const float*)d_in[5];
  const float* fc3_b = (const float*)d_in[6];
  const float* fc4_w = (const float*)d_in[7];
  const float* fc4_b = (const float*)d_in[8];
  const float* fc5_w = (const float*)d_in[9];
  const float* fc5_b = (const float*)d_in[10];
  const float* pre_w = (const float*)d_in[11];
  const float* pre_b = (const float*)d_in[12];
  const float* pos_w = (const float*)d_in[13];
  const float* enc_w = (const float*)d_in[14];
  const float* enc_b = (const float*)d_in[15];
  const float* ln1_g = (const float*)d_in[16];
  const float* ln1_b = (const float*)d_in[17];
  const float* ln2_g = (const float*)d_in[18];
  const float* ln2_b = (const float*)d_in[19];
  const float* res_w1 = (const float*)d_in[20];
  const float* res_b1 = (const float*)d_in[21];
  const float* res_w2 = (const float*)d_in[22];
  const float* res_b2 = (const float*)d_in[23];
  const float* out_w = (const float*)d_in[24];
  const float* out_b = (const float*)d_in[25];

  char* ws = (char*)d_ws;
  _Float16* wbuf = (_Float16*)ws;                    // 33.5 MB
  _Float16* bufA = (_Float16*)(ws + 33554432);       // 33.5 MB
  char* bufB = ws + 67108864;                        // 33.5 MB
  _Float16* qkv16 = bufA + 1048576;                  // 4096*768
  _Float16* h16 = bufA + 4194304;                    // 4096*1024
  _Float16* x16 = bufA + 8388608;                    // 4096*256
  // bufB layout (byte offsets):
  float* xres = (float*)(bufB + 4194304);            // 4 MB  (residual A)
  float* aout = (float*)(bufB + 8388608);            // 4 MB
  float* xres2 = (float*)(bufB + 12582912);          // 4 MB  (residual B)
  float* enc32 = (float*)(bufB + 16777216);          // 2 MB
  float* stats = (float*)(bufB + 18874368);          // 8 B
  _Float16* encT = (_Float16*)(bufB + 20971520);     // 3 MB
  _Float16* res1T = encT + 1572864;                  // 4 MB
  _Float16* res2T = res1T + 2097152;                 // 4 MB
  _Float16* outT = res2T + 2097152;                  // 64 KB

  const dim3 tb(256);

  // ---- trunk ----
  cast_k<<<16384, tb, 0, stream>>>(state, bufA, 16777216);
  tcast_k<<<dim3(128, 128), tb, 0, stream>>>(fc1_w, wbuf, 4096, 4096);
  gemm_nt<128, 128, 64, 2, 2, 0><<<dim3(32, 32), tb, 0, stream>>>(bufA, wbuf, fc1_b, (_Float16*)bufB, nullptr, nullptr, nullptr, 4096, 4096, 4096);
  tcast_k<<<dim3(64, 128), tb, 0, stream>>>(fc2_w, wbuf, 4096, 2048);
  gemm_nt<128, 128, 64, 2, 2, 0><<<dim3(16, 32), tb, 0, stream>>>((_Float16*)bufB, wbuf, fc2_b, bufA, nullptr, nullptr, nullptr, 4096, 2048, 4096);
  tcast_k<<<dim3(32, 64), tb, 0, stream>>>(fc3_w, wbuf, 2048, 1024);
  gemm_nt<128, 64, 64, 2, 2, 0><<<dim3(16, 32), tb, 0, stream>>>(bufA, wbuf, fc3_b, (_Float16*)bufB, nullptr, nullptr, nullptr, 4096, 1024, 2048);
  tcast_k<<<dim3(16, 32), tb, 0, stream>>>(fc4_w, wbuf, 1024, 512);
  gemm_nt<64, 64, 128, 2, 2, 0><<<dim3(8, 64), tb, 0, stream>>>((_Float16*)bufB, wbuf, fc4_b, bufA, nullptr, nullptr, nullptr, 4096, 512, 1024);
  tcast_k<<<dim3(8, 16), tb, 0, stream>>>(fc5_w, wbuf, 512, 256);
  gemm_nt<64, 64, 256, 2, 2, 1><<<dim3(4, 64), tb, 0, stream>>>(bufA, wbuf, fc5_b, (_Float16*)bufB, nullptr, nullptr, nullptr, 4096, 256, 512);
  tcast_k<<<dim3(8, 8), tb, 0, stream>>>(pre_w, wbuf, 256, 256);
  gemm_nt<64, 64, 256, 2, 2, 3><<<dim3(4, 64), tb, 0, stream>>>((_Float16*)bufB, wbuf, pre_b, nullptr, xres, pos_w, nullptr, 4096, 256, 256);

  // ---- all per-layer weight transposes in one launch ----
  tcast_all<<<5664, tb, 0, stream>>>(enc_w, encT, res_w1, res1T, res_w2, res2T, out_w, outT);

  // ---- transformer blocks (residual ping-pong to avoid LN read/write race) ----
  for (int l = 0; l < 8; l++) {
    float* R = (l & 1) ? xres2 : xres;
    float* S = (l & 1) ? xres : xres2;
    gemm_ln<2, false><<<dim3(12, 64), tb, 0, stream>>>(R, nullptr, ln1_g + l * 256, ln1_b + l * 256,
                                                       encT + (size_t)l * 196608, enc_b + l * 768, qkv16, nullptr, 768);
    attn_k<<<512, tb, 0, stream>>>(qkv16, aout);
    gemm_ln<4, true><<<dim3(16, 64), tb, 0, stream>>>(R, aout, ln2_g + l * 256, ln2_b + l * 256,
                                                      res1T + (size_t)l * 262144, res_b1 + l * 1024, h16, S, 1024);
    gemm_nt<64, 64, 128, 2, 2, 5><<<dim3(4, 64), tb, 0, stream>>>(h16, res2T + (size_t)l * 262144, res_b2 + l * 256,
                                                                  x16, S, S, nullptr, 4096, 256, 1024);
  }

  // ---- output projection (+inline stats) + standardization ----
  hipMemsetAsync(stats, 0, 2 * sizeof(float), stream);
  gemm_nt<64, 64, 256, 2, 2, 7><<<dim3(2, 64), tb, 0, stream>>>(x16, outT, out_b, nullptr, enc32, nullptr, stats, 4096, 128, 256);
  finalize_k<<<512, tb, 0, stream>>>((const float4*)enc32, stats, (float4*)d_out, 131072, 524288.0f);
}

// Round 5
// 1452.296 us; speedup vs baseline: 1.1836x; 1.1836x over previous
//
#include <hip/hip_runtime.h>

typedef _Float16 half8 __attribute__((ext_vector_type(8)));
typedef _Float16 half4v __attribute__((ext_vector_type(4)));
typedef _Float16 half2v __attribute__((ext_vector_type(2)));
typedef float f32x4 __attribute__((ext_vector_type(4)));

__device__ __forceinline__ void gload16(const _Float16* g, _Float16* l) {
  __builtin_amdgcn_global_load_lds((const __attribute__((address_space(1))) void*)g,
                                   (__attribute__((address_space(3))) void*)l, 16, 0, 0);
}

// ---------------------------------------------------------------------------
__global__ __launch_bounds__(256) void cast_k(const float* __restrict__ in,
                                              _Float16* __restrict__ out, int n) {
  int i = (blockIdx.x * 256 + threadIdx.x) << 2;
  if (i < n) {
    float4 v = *(const float4*)(in + i);
    half4v h;
    h[0] = (_Float16)v.x; h[1] = (_Float16)v.y; h[2] = (_Float16)v.z; h[3] = (_Float16)v.w;
    *(half4v*)(out + i) = h;
  }
}

// ---------------------------------------------------------------------------
// Transpose+cast, 64n x 32k tile per block, coalesced reads AND 16B/lane writes.
// W[K][N] fp32 -> WT[N][K] fp16.
__device__ __forceinline__ void t2core(const float* __restrict__ W, _Float16* __restrict__ WT,
                                       int K, int N, int n0, int k0, float (*tile)[65]) {
  const int tid = threadIdx.x;
  const int n = tid & 63, kq = tid >> 6;  // 4 waves, each 8 k-rows
#pragma unroll
  for (int i = 0; i < 8; i++)
    tile[kq * 8 + i][n] = W[(size_t)(k0 + kq * 8 + i) * N + n0 + n];
  __syncthreads();
  const int nn = tid >> 2, c = tid & 3;   // lane writes 8 consecutive k as half8
  half8 h;
#pragma unroll
  for (int j = 0; j < 8; j++) h[j] = (_Float16)tile[c * 8 + j][nn];
  *(half8*)(WT + (size_t)(n0 + nn) * K + k0 + c * 8) = h;
}

__global__ __launch_bounds__(256) void t2_k(const float* __restrict__ W,
                                            _Float16* __restrict__ WT, int K, int N) {
  __shared__ float tile[32][65];
  t2core(W, WT, K, N, blockIdx.x << 6, blockIdx.y << 5, tile);
}

// every non-fc1 weight in one launch (8304 blocks)
__global__ __launch_bounds__(256) void tcast_comb(
    const float* __restrict__ fc2_w, _Float16* fc2T,
    const float* __restrict__ fc3_w, _Float16* fc3T,
    const float* __restrict__ fc4_w, _Float16* fc4T,
    const float* __restrict__ fc5_w, _Float16* fc5T,
    const float* __restrict__ pre_w, _Float16* preT,
    const float* __restrict__ enc_w, _Float16* encT,
    const float* __restrict__ res_w1, _Float16* res1T,
    const float* __restrict__ res_w2, _Float16* res2T,
    const float* __restrict__ out_w, _Float16* outT) {
  __shared__ float tile[32][65];
  int b = blockIdx.x;
  const float* W; _Float16* WT; int K, N, n0, k0;
  if (b < 4096)               { W = fc2_w; WT = fc2T; K = 4096; N = 2048; n0 = (b & 31) << 6; k0 = (b >> 5) << 5; }
  else if ((b -= 4096) < 1024){ W = fc3_w; WT = fc3T; K = 2048; N = 1024; n0 = (b & 15) << 6; k0 = (b >> 4) << 5; }
  else if ((b -= 1024) < 256) { W = fc4_w; WT = fc4T; K = 1024; N = 512;  n0 = (b & 7) << 6;  k0 = (b >> 3) << 5; }
  else if ((b -= 256) < 64)   { W = fc5_w; WT = fc5T; K = 512;  N = 256;  n0 = (b & 3) << 6;  k0 = (b >> 2) << 5; }
  else if ((b -= 64) < 32)    { W = pre_w; WT = preT; K = 256;  N = 256;  n0 = (b & 3) << 6;  k0 = (b >> 2) << 5; }
  else if ((b -= 32) < 768)   { int z = b / 96, r = b % 96;
                                W = enc_w + (size_t)z * 196608; WT = encT + (size_t)z * 196608;
                                K = 256; N = 768; n0 = (r % 12) << 6; k0 = (r / 12) << 5; }
  else if ((b -= 768) < 1024) { int z = b >> 7, r = b & 127;
                                W = res_w1 + (size_t)z * 262144; WT = res1T + (size_t)z * 262144;
                                K = 256; N = 1024; n0 = (r & 15) << 6; k0 = (r >> 4) << 5; }
  else if ((b -= 1024) < 1024){ int z = b >> 7, r = b & 127;
                                W = res_w2 + (size_t)z * 262144; WT = res2T + (size_t)z * 262144;
                                K = 1024; N = 256; n0 = (r & 3) << 6; k0 = (r >> 2) << 5; }
  else                        { b -= 1024; W = out_w; WT = outT; K = 256; N = 128; n0 = (b & 1) << 6; k0 = (b >> 1) << 5; }
  t2core(W, WT, K, N, n0, k0, tile);
}

// ---------------------------------------------------------------------------
// NT GEMM: C[M,N] = epilogue(A[M,K] @ Bt[N,K]^T + bias), XOR-swizzled LDS.
// MODE: 0 relu->H | 1 tanh->H | 2 bias->H | 3 +pos->F | 4 gelu->H | 5 +aux->F&H | 7 ->F+stats
template <int BM, int BN, int BK, int WGM, int WGN, int MODE>
__global__ __launch_bounds__(256) void gemm_nt(const _Float16* __restrict__ A,
                                               const _Float16* __restrict__ Bt,
                                               const float* __restrict__ bias,
                                               _Float16* __restrict__ outH,
                                               float* __restrict__ outF,
                                               const float* __restrict__ aux,
                                               float* __restrict__ stats,
                                               int M, int N, int K) {
  constexpr int CPR = BK / 8;
  constexpr int TM = BM / WGM, TN = BN / WGN;
  constexpr int AM = TM / 16, AN = TN / 16;
  constexpr int LA = BM * BK / 2048, LB = BN * BK / 2048;
  __shared__ __align__(16) _Float16 As[BM * BK];
  __shared__ __align__(16) _Float16 Bs[BN * BK];
  const int tid = threadIdx.x;
  const int lane = tid & 63, w = tid >> 6;
  const int wr = (w / WGN) * TM, wc = (w % WGN) * TN;
  const int lr = lane & 15, quad = lane >> 4;
  const int mb = blockIdx.y * BM, nb = blockIdx.x * BN;

  const _Float16* ga[LA];
  const _Float16* gb[LB];
  _Float16* la[LA];
  _Float16* lb[LB];
#pragma unroll
  for (int i = 0; i < LA; i++) {
    const int c = tid + i * 256, row = c / CPR, j = c % CPR;
    ga[i] = A + (size_t)(mb + row) * K + ((j ^ (row & 7)) << 3);
    la[i] = As + c * 8;
  }
#pragma unroll
  for (int i = 0; i < LB; i++) {
    const int c = tid + i * 256, row = c / CPR, j = c % CPR;
    gb[i] = Bt + (size_t)(nb + row) * K + ((j ^ (row & 7)) << 3);
    lb[i] = Bs + c * 8;
  }

  f32x4 acc[AM][AN] = {};

  for (int k0 = 0; k0 < K; k0 += BK) {
#pragma unroll
    for (int i = 0; i < LA; i++) gload16(ga[i] + k0, la[i]);
#pragma unroll
    for (int i = 0; i < LB; i++) gload16(gb[i] + k0, lb[i]);
    __syncthreads();
#pragma unroll
    for (int ks = 0; ks < BK / 32; ks++) {
      const int pc = (((ks << 2) | quad) ^ (lane & 7)) << 3;
      half8 af[AM], bf[AN];
#pragma unroll
      for (int mt = 0; mt < AM; mt++)
        af[mt] = *(const half8*)(As + (wr + mt * 16 + lr) * BK + pc);
#pragma unroll
      for (int nt = 0; nt < AN; nt++)
        bf[nt] = *(const half8*)(Bs + (wc + nt * 16 + lr) * BK + pc);
#pragma unroll
      for (int mt = 0; mt < AM; mt++)
#pragma unroll
        for (int nt = 0; nt < AN; nt++)
          acc[mt][nt] = __builtin_amdgcn_mfma_f32_16x16x32_f16(af[mt], bf[nt], acc[mt][nt], 0, 0, 0);
    }
    __syncthreads();
  }

  float ls = 0.0f, lsq = 0.0f;
#pragma unroll
  for (int nt = 0; nt < AN; nt++) {
    const int col = nb + wc + (nt << 4) + lr;
    const float bv = bias[col];
#pragma unroll
    for (int mt = 0; mt < AM; mt++) {
      const int row0 = mb + wr + (mt << 4) + (quad << 2);
#pragma unroll
      for (int r = 0; r < 4; r++) {
        const int row = row0 + r;
        const size_t off = (size_t)row * N + col;
        float v = acc[mt][nt][r] + bv;
        if (MODE == 0) {
          outH[off] = (_Float16)fmaxf(v, 0.0f);
        } else if (MODE == 1) {
          outH[off] = (_Float16)tanhf(v);
        } else if (MODE == 2) {
          outH[off] = (_Float16)v;
        } else if (MODE == 3) {
          outF[off] = v + aux[(size_t)(row & 511) * N + col];  // + pos_w[s]
        } else if (MODE == 4) {
          outH[off] = (_Float16)(0.5f * v * (1.0f + erff(v * 0.70710678118654752f)));
        } else if (MODE == 5) {
          float xv = aux[off] + v;  // residual add
          outF[off] = xv;
          outH[off] = (_Float16)xv;
        } else {
          outF[off] = v;
          if (MODE == 7) { ls += v; lsq += v * v; }
        }
      }
    }
  }
  if (MODE == 7) {
#pragma unroll
    for (int o = 32; o; o >>= 1) { ls += __shfl_xor(ls, o); lsq += __shfl_xor(lsq, o); }
    if (lane == 0) {
      atomicAdd(&stats[0], ls);
      atomicAdd(&stats[1], lsq);
    }
  }
}

// ---------------------------------------------------------------------------
// LayerNorm over D=256; 4 rows/block. xn = fp16(LN(x))
__global__ __launch_bounds__(256) void ln_k(const float* __restrict__ x,
                                            const float* __restrict__ g,
                                            const float* __restrict__ b,
                                            _Float16* __restrict__ xn) {
  const int w = threadIdx.x >> 6, lane = threadIdx.x & 63;
  const int row = (blockIdx.x << 2) + w;
  const size_t base = ((size_t)row << 8) + (lane << 2);
  float4 v = *(const float4*)(x + base);
  float s = v.x + v.y + v.z + v.w;
  float sq = v.x * v.x + v.y * v.y + v.z * v.z + v.w * v.w;
#pragma unroll
  for (int o = 32; o; o >>= 1) { s += __shfl_xor(s, o); sq += __shfl_xor(sq, o); }
  const float mean = s * 0.00390625f;
  const float rs = rsqrtf(sq * 0.00390625f - mean * mean + 1e-5f);
  const int c = lane << 2;
  float4 gv = *(const float4*)(g + c);
  float4 bv = *(const float4*)(b + c);
  half4v o4;
  o4[0] = (_Float16)((v.x - mean) * rs * gv.x + bv.x);
  o4[1] = (_Float16)((v.y - mean) * rs * gv.y + bv.y);
  o4[2] = (_Float16)((v.z - mean) * rs * gv.z + bv.z);
  o4[3] = (_Float16)((v.w - mean) * rs * gv.w + bv.w);
  *(half4v*)(xn + base) = o4;
}

// x' = LN(x + a); writes x' fp32 and fp16 copy
__global__ __launch_bounds__(256) void add_ln_k(const float* __restrict__ x,
                                                const float* __restrict__ a,
                                                const float* __restrict__ g,
                                                const float* __restrict__ b,
                                                float* __restrict__ xo,
                                                _Float16* __restrict__ xn) {
  const int w = threadIdx.x >> 6, lane = threadIdx.x & 63;
  const int row = (blockIdx.x << 2) + w;
  const size_t base = ((size_t)row << 8) + (lane << 2);
  float4 v = *(const float4*)(x + base);
  float4 av = *(const float4*)(a + base);
  v.x += av.x; v.y += av.y; v.z += av.z; v.w += av.w;
  float s = v.x + v.y + v.z + v.w;
  float sq = v.x * v.x + v.y * v.y + v.z * v.z + v.w * v.w;
#pragma unroll
  for (int o = 32; o; o >>= 1) { s += __shfl_xor(s, o); sq += __shfl_xor(sq, o); }
  const float mean = s * 0.00390625f;
  const float rs = rsqrtf(sq * 0.00390625f - mean * mean + 1e-5f);
  const int c = lane << 2;
  float4 gv = *(const float4*)(g + c);
  float4 bv = *(const float4*)(b + c);
  float4 o4;
  o4.x = (v.x - mean) * rs * gv.x + bv.x;
  o4.y = (v.y - mean) * rs * gv.y + bv.y;
  o4.z = (v.z - mean) * rs * gv.z + bv.z;
  o4.w = (v.w - mean) * rs * gv.w + bv.w;
  *(float4*)(xo + base) = o4;
  half4v h;
  h[0] = (_Float16)o4.x; h[1] = (_Float16)o4.y; h[2] = (_Float16)o4.z; h[3] = (_Float16)o4.w;
  *(half4v*)(xn + base) = h;
}

// ---------------------------------------------------------------------------
// Causal flash attention. Block = (b, h, 64-row q-tile); 512 blocks.
// K/V strip staged fp16 in LDS once; 4-way kv-split; K rows read as half8 (b128).
#define HP0(v) ((half2v)__builtin_shufflevector((v), (v), 0, 1))
#define HP1(v) ((half2v)__builtin_shufflevector((v), (v), 2, 3))
#define HP2(v) ((half2v)__builtin_shufflevector((v), (v), 4, 5))
#define HP3(v) ((half2v)__builtin_shufflevector((v), (v), 6, 7))
__device__ __forceinline__ float dot8(half8 a, half8 b, float acc) {
  acc = __builtin_amdgcn_fdot2(HP0(a), HP0(b), acc, false);
  acc = __builtin_amdgcn_fdot2(HP1(a), HP1(b), acc, false);
  acc = __builtin_amdgcn_fdot2(HP2(a), HP2(b), acc, false);
  acc = __builtin_amdgcn_fdot2(HP3(a), HP3(b), acc, false);
  return acc;
}
__global__ __launch_bounds__(256) void attn_k(const _Float16* __restrict__ qkv,
                                              float* __restrict__ aout) {
  __shared__ __align__(16) char smem[65536];
  _Float16* Ks = (_Float16*)smem;
  _Float16* Vs = (_Float16*)(smem + 32768);
  float* Om = (float*)smem;
  float* Ol = (float*)(smem + 768);
  float* Os = (float*)(smem + 1536);

  const int bid = blockIdx.x;
  const int qt = 7 - (bid & 7), h = (bid >> 3) & 7, b = bid >> 6;
  const int q0 = qt << 6;
  const int t = threadIdx.x, p = t >> 6, tr = t & 63, q = q0 + tr;
  const int nkt = qt + 1;
  const size_t rowbase = (size_t)(b * 512) * 768;

  const half8* qr = (const half8*)(qkv + rowbase + (size_t)q * 768 + h * 32);
  half8 qf0 = qr[0], qf1 = qr[1], qf2 = qr[2], qf3 = qr[3];

  for (int c = t; c < nkt * 256; c += 256) {
    const int row = c >> 2, off = (c & 3) << 3;
    const _Float16* kp = qkv + rowbase + (size_t)row * 768 + 256 + h * 32 + off;
    gload16(kp, Ks + c * 8);
    gload16(kp + 256, Vs + c * 8);
  }
  __syncthreads();

  float O[32];
#pragma unroll
  for (int d = 0; d < 32; d++) O[d] = 0.0f;
  float m = -1e30f, lsum = 0.0f;

  for (int kt = p; kt < nkt; kt += 4) {
    const int kb = kt << 6;
    const int rows = (kt == qt) ? (tr + 1) : 64;
    for (int j0 = 0; j0 < rows; j0 += 8) {
      float s[8];
      float mx = -1e30f;
#pragma unroll
      for (int jj = 0; jj < 8; jj++) {
        const half8* kr = (const half8*)(Ks + (size_t)(kb + j0 + jj) * 32);
        float a0 = 0.0f, a1 = 0.0f, a2 = 0.0f, a3 = 0.0f;
        a0 = dot8(qf0, kr[0], a0);
        a1 = dot8(qf1, kr[1], a1);
        a2 = dot8(qf2, kr[2], a2);
        a3 = dot8(qf3, kr[3], a3);
        const float sc = ((a0 + a1) + (a2 + a3)) * 0.17677669529663687f;
        s[jj] = (kb + j0 + jj <= q) ? sc : -1e30f;
        mx = fmaxf(mx, s[jj]);
      }
      const float mn = fmaxf(m, mx);
      const float corr = __expf(m - mn);
      lsum *= corr;
#pragma unroll
      for (int d = 0; d < 32; d++) O[d] *= corr;
      m = mn;
#pragma unroll
      for (int jj = 0; jj < 8; jj++) {
        const float pw = __expf(s[jj] - m);
        lsum += pw;
        const half8* vr = (const half8*)(Vs + (size_t)(kb + j0 + jj) * 32);
#pragma unroll
        for (int i = 0; i < 4; i++) {
          half8 vv = vr[i];
#pragma unroll
          for (int d = 0; d < 8; d++) O[i * 8 + d] = fmaf(pw, (float)vv[d], O[i * 8 + d]);
        }
      }
    }
  }

  __syncthreads();
  if (p > 0) {
    Om[(p - 1) * 64 + tr] = m;
    Ol[(p - 1) * 64 + tr] = lsum;
    float* od = Os + ((p - 1) * 64 + tr) * 33;
#pragma unroll
    for (int d = 0; d < 32; d++) od[d] = O[d];
  }
  __syncthreads();
  if (p == 0) {
    float mn = m;
#pragma unroll
    for (int pp = 0; pp < 3; pp++) mn = fmaxf(mn, Om[pp * 64 + tr]);
    const float c0 = __expf(m - mn);
    float lt = lsum * c0;
    float cs[3];
#pragma unroll
    for (int pp = 0; pp < 3; pp++) {
      cs[pp] = __expf(Om[pp * 64 + tr] - mn);
      lt += Ol[pp * 64 + tr] * cs[pp];
    }
    const float inv = 1.0f / lt;
    float* op = aout + ((size_t)(b * 512 + q)) * 256 + h * 32;
#pragma unroll
    for (int d = 0; d < 32; d++) {
      float v = O[d] * c0;
#pragma unroll
      for (int pp = 0; pp < 3; pp++) v += Os[(pp * 64 + tr) * 33 + d] * cs[pp];
      op[d] = v * inv;
    }
  }
}

// ---------------------------------------------------------------------------
__global__ __launch_bounds__(256) void finalize_k(const float4* __restrict__ enc,
                                                  const float* __restrict__ stats,
                                                  float4* __restrict__ out, int n4, float n) {
  const int i = blockIdx.x * 256 + threadIdx.x;
  if (i >= n4) return;
  const float s = stats[0], q = stats[1];
  const float mean = s / n;
  const float var = (q - s * s / n) / (n - 1.0f);  // ddof=1
  const float inv = rsqrtf(var);
  float4 x = enc[i];
  float4 o;
  o.x = (x.x - mean) * inv + 1e-10f;
  o.y = (x.y - mean) * inv + 1e-10f;
  o.z = (x.z - mean) * inv + 1e-10f;
  o.w = (x.w - mean) * inv + 1e-10f;
  out[i] = o;
}

// ---------------------------------------------------------------------------
extern "C" void kernel_launch(void* const* d_in, const int* in_sizes, int n_in,
                              void* d_out, int out_size, void* d_ws, size_t ws_size,
                              hipStream_t stream) {
  const float* state = (const float*)d_in[0];
  const float* fc1_w = (const float*)d_in[1];
  const float* fc1_b = (const float*)d_in[2];
  const float* fc2_w = (const float*)d_in[3];
  const float* fc2_b = (const float*)d_in[4];
  const float* fc3_w = (const float*)d_in[5];
  const float* fc3_b = (const float*)d_in[6];
  const float* fc4_w = (const float*)d_in[7];
  const float* fc4_b = (const float*)d_in[8];
  const float* fc5_w = (const float*)d_in[9];
  const float* fc5_b = (const float*)d_in[10];
  const float* pre_w = (const float*)d_in[11];
  const float* pre_b = (const float*)d_in[12];
  const float* pos_w = (const float*)d_in[13];
  const float* enc_w = (const float*)d_in[14];
  const float* enc_b = (const float*)d_in[15];
  const float* ln1_g = (const float*)d_in[16];
  const float* ln1_b = (const float*)d_in[17];
  const float* ln2_g = (const float*)d_in[18];
  const float* ln2_b = (const float*)d_in[19];
  const float* res_w1 = (const float*)d_in[20];
  const float* res_b1 = (const float*)d_in[21];
  const float* res_w2 = (const float*)d_in[22];
  const float* res_b2 = (const float*)d_in[23];
  const float* out_w = (const float*)d_in[24];
  const float* out_b = (const float*)d_in[25];

  char* ws = (char*)d_ws;
  _Float16* wbuf = (_Float16*)ws;                       // 32 MiB
  _Float16* bufA16 = (_Float16*)(ws + (32 << 20));      // 32 MiB
  char* bufB = ws + (64 << 20);                         // 32 MiB

  // wbuf sub-allocs (half elements):
  _Float16* fc2T = wbuf;                 // [0,16Mi)
  _Float16* fc3T = wbuf + 8388608;       // [16,20Mi)
  _Float16* fc4T = wbuf + 10485760;      // [20,21Mi)
  _Float16* encT = wbuf + 11010048;      // [21,24Mi)
  _Float16* res1T = wbuf + 12582912;     // [24,28Mi)
  _Float16* res2T = wbuf + 14680064;     // [28,32Mi)
  // bufA tail (above all trunk/layer activations):
  _Float16* fc5T = bufA16 + 14680064;    // 28Mi
  _Float16* preT = bufA16 + 14811136;
  _Float16* outT = bufA16 + 14876672;
  // bufA activation sub-allocs:
  _Float16* xn16 = bufA16;               // 2 MiB
  _Float16* qkv16 = bufA16 + 1048576;    // 6 MiB
  _Float16* h16 = bufA16 + 4194304;      // 8 MiB
  _Float16* x16 = bufA16 + 8388608;      // 2 MiB
  // bufB sub-allocs (bytes):
  float* xres = (float*)(bufB + 8388608);    // 4 MiB
  float* aout = (float*)(bufB + 12582912);   // 4 MiB
  float* enc32 = (float*)(bufB + 20971520);  // 2 MiB
  float* stats = (float*)(bufB + 23068672);  // 8 B

  const dim3 tb(256);

  // ---- trunk ----
  cast_k<<<16384, tb, 0, stream>>>(state, bufA16, 16777216);
  t2_k<<<dim3(64, 128), tb, 0, stream>>>(fc1_w, wbuf, 4096, 4096);
  gemm_nt<128, 128, 64, 2, 2, 0><<<dim3(32, 32), tb, 0, stream>>>(bufA16, wbuf, fc1_b, (_Float16*)bufB, nullptr, nullptr, nullptr, 4096, 4096, 4096);
  tcast_comb<<<8304, tb, 0, stream>>>(fc2_w, fc2T, fc3_w, fc3T, fc4_w, fc4T, fc5_w, fc5T,
                                      pre_w, preT, enc_w, encT, res_w1, res1T, res_w2, res2T, out_w, outT);
  gemm_nt<128, 128, 64, 2, 2, 0><<<dim3(16, 32), tb, 0, stream>>>((_Float16*)bufB, fc2T, fc2_b, bufA16, nullptr, nullptr, nullptr, 4096, 2048, 4096);
  gemm_nt<128, 128, 64, 2, 2, 0><<<dim3(8, 32), tb, 0, stream>>>(bufA16, fc3T, fc3_b, (_Float16*)bufB, nullptr, nullptr, nullptr, 4096, 1024, 2048);
  gemm_nt<128, 64, 64, 4, 1, 0><<<dim3(8, 32), tb, 0, stream>>>((_Float16*)bufB, fc4T, fc4_b, bufA16, nullptr, nullptr, nullptr, 4096, 512, 1024);
  gemm_nt<64, 64, 64, 2, 2, 1><<<dim3(4, 64), tb, 0, stream>>>(bufA16, fc5T, fc5_b, (_Float16*)bufB, nullptr, nullptr, nullptr, 4096, 256, 512);
  gemm_nt<64, 64, 64, 2, 2, 3><<<dim3(4, 64), tb, 0, stream>>>((_Float16*)bufB, preT, pre_b, nullptr, xres, pos_w, nullptr, 4096, 256, 256);

  // ---- transformer blocks ----
  for (int l = 0; l < 8; l++) {
    ln_k<<<1024, tb, 0, stream>>>(xres, ln1_g + l * 256, ln1_b + l * 256, xn16);
    gemm_nt<128, 64, 64, 4, 1, 2><<<dim3(12, 32), tb, 0, stream>>>(xn16, encT + (size_t)l * 196608, enc_b + l * 768,
                                                                   qkv16, nullptr, nullptr, nullptr, 4096, 768, 256);
    attn_k<<<512, tb, 0, stream>>>(qkv16, aout);
    add_ln_k<<<1024, tb, 0, stream>>>(xres, aout, ln2_g + l * 256, ln2_b + l * 256, xres, xn16);
    gemm_nt<128, 128, 64, 2, 2, 4><<<dim3(8, 32), tb, 0, stream>>>(xn16, res1T + (size_t)l * 262144, res_b1 + l * 1024,
                                                                   h16, nullptr, nullptr, nullptr, 4096, 1024, 256);
    gemm_nt<64, 64, 64, 2, 2, 5><<<dim3(4, 64), tb, 0, stream>>>(h16, res2T + (size_t)l * 262144, res_b2 + l * 256,
                                                                 x16, xres, xres, nullptr, 4096, 256, 1024);
  }

  // ---- output projection (+inline stats) + standardization ----
  (void)hipMemsetAsync(stats, 0, 2 * sizeof(float), stream);
  gemm_nt<64, 64, 64, 2, 2, 7><<<dim3(2, 64), tb, 0, stream>>>(x16, outT, out_b, nullptr, enc32, nullptr, stats, 4096, 128, 256);
  finalize_k<<<512, tb, 0, stream>>>((const float4*)enc32, stats, (float4*)d_out, 131072, 524288.0f);
}

// Round 6
// 1438.159 us; speedup vs baseline: 1.1952x; 1.0098x over previous
//
#include <hip/hip_runtime.h>

typedef _Float16 half8 __attribute__((ext_vector_type(8)));
typedef _Float16 half4v __attribute__((ext_vector_type(4)));
typedef _Float16 half2v __attribute__((ext_vector_type(2)));
typedef float f32x4 __attribute__((ext_vector_type(4)));
typedef float f32x16 __attribute__((ext_vector_type(16)));

__device__ __forceinline__ void gload16(const _Float16* g, _Float16* l) {
  __builtin_amdgcn_global_load_lds((const __attribute__((address_space(1))) void*)g,
                                   (__attribute__((address_space(3))) void*)l, 16, 0, 0);
}

// ---------------------------------------------------------------------------
__global__ __launch_bounds__(256) void cast_k(const float* __restrict__ in,
                                              _Float16* __restrict__ out, int n) {
  int i = (blockIdx.x * 256 + threadIdx.x) << 2;
  if (i < n) {
    float4 v = *(const float4*)(in + i);
    half4v h;
    h[0] = (_Float16)v.x; h[1] = (_Float16)v.y; h[2] = (_Float16)v.z; h[3] = (_Float16)v.w;
    *(half4v*)(out + i) = h;
  }
}

// ---------------------------------------------------------------------------
// Transpose+cast, 64n x 32k tile per block. W[K][N] fp32 -> WT[N][K] fp16.
__device__ __forceinline__ void t2core(const float* __restrict__ W, _Float16* __restrict__ WT,
                                       int K, int N, int n0, int k0, float (*tile)[65]) {
  const int tid = threadIdx.x;
  const int n = tid & 63, kq = tid >> 6;
#pragma unroll
  for (int i = 0; i < 8; i++)
    tile[kq * 8 + i][n] = W[(size_t)(k0 + kq * 8 + i) * N + n0 + n];
  __syncthreads();
  const int nn = tid >> 2, c = tid & 3;
  half8 h;
#pragma unroll
  for (int j = 0; j < 8; j++) h[j] = (_Float16)tile[c * 8 + j][nn];
  *(half8*)(WT + (size_t)(n0 + nn) * K + k0 + c * 8) = h;
}

__global__ __launch_bounds__(256) void t2_k(const float* __restrict__ W,
                                            _Float16* __restrict__ WT, int K, int N) {
  __shared__ float tile[32][65];
  t2core(W, WT, K, N, blockIdx.x << 6, blockIdx.y << 5, tile);
}

// every non-fc1 weight in one launch (8304 blocks)
__global__ __launch_bounds__(256) void tcast_comb(
    const float* __restrict__ fc2_w, _Float16* fc2T,
    const float* __restrict__ fc3_w, _Float16* fc3T,
    const float* __restrict__ fc4_w, _Float16* fc4T,
    const float* __restrict__ fc5_w, _Float16* fc5T,
    const float* __restrict__ pre_w, _Float16* preT,
    const float* __restrict__ enc_w, _Float16* encT,
    const float* __restrict__ res_w1, _Float16* res1T,
    const float* __restrict__ res_w2, _Float16* res2T,
    const float* __restrict__ out_w, _Float16* outT) {
  __shared__ float tile[32][65];
  int b = blockIdx.x;
  const float* W; _Float16* WT; int K, N, n0, k0;
  if (b < 4096)               { W = fc2_w; WT = fc2T; K = 4096; N = 2048; n0 = (b & 31) << 6; k0 = (b >> 5) << 5; }
  else if ((b -= 4096) < 1024){ W = fc3_w; WT = fc3T; K = 2048; N = 1024; n0 = (b & 15) << 6; k0 = (b >> 4) << 5; }
  else if ((b -= 1024) < 256) { W = fc4_w; WT = fc4T; K = 1024; N = 512;  n0 = (b & 7) << 6;  k0 = (b >> 3) << 5; }
  else if ((b -= 256) < 64)   { W = fc5_w; WT = fc5T; K = 512;  N = 256;  n0 = (b & 3) << 6;  k0 = (b >> 2) << 5; }
  else if ((b -= 64) < 32)    { W = pre_w; WT = preT; K = 256;  N = 256;  n0 = (b & 3) << 6;  k0 = (b >> 2) << 5; }
  else if ((b -= 32) < 768)   { int z = b / 96, r = b % 96;
                                W = enc_w + (size_t)z * 196608; WT = encT + (size_t)z * 196608;
                                K = 256; N = 768; n0 = (r % 12) << 6; k0 = (r / 12) << 5; }
  else if ((b -= 768) < 1024) { int z = b >> 7, r = b & 127;
                                W = res_w1 + (size_t)z * 262144; WT = res1T + (size_t)z * 262144;
                                K = 256; N = 1024; n0 = (r & 15) << 6; k0 = (r >> 4) << 5; }
  else if ((b -= 1024) < 1024){ int z = b >> 7, r = b & 127;
                                W = res_w2 + (size_t)z * 262144; WT = res2T + (size_t)z * 262144;
                                K = 1024; N = 256; n0 = (r & 3) << 6; k0 = (r >> 2) << 5; }
  else                        { b -= 1024; W = out_w; WT = outT; K = 256; N = 128; n0 = (b & 1) << 6; k0 = (b >> 1) << 5; }
  t2core(W, WT, K, N, n0, k0, tile);
}

// ---------------------------------------------------------------------------
// NT GEMM on 32x32x16 MFMA: C[M,N] = epilogue(A[M,K] @ Bt[N,K]^T + bias).
// XOR-swizzled LDS (chunk j of row r holds logical chunk j^(r&7); staging fetches
// permuted global chunk so global_load_lds stays contiguous, fragments 2-way/bank).
// A/B frag: lane = m + 32*(k/8), 8 contiguous k (half8).
// C/D frag: col = lane&31, row = (reg&3) + 8*(reg>>2) + 4*(lane>>5), reg in [0,16).
// MODE: 0 relu->H | 1 tanh->H | 2 bias->H | 3 +pos->F | 4 gelu->H | 5 +aux->F&H | 7 ->F+stats
template <int BM, int BN, int BK, int WGM, int WGN, int MODE>
__global__ __launch_bounds__(256) void gemm_nt(const _Float16* __restrict__ A,
                                               const _Float16* __restrict__ Bt,
                                               const float* __restrict__ bias,
                                               _Float16* __restrict__ outH,
                                               float* __restrict__ outF,
                                               const float* __restrict__ aux,
                                               float* __restrict__ stats,
                                               int M, int N, int K) {
  constexpr int CPR = BK / 8;
  constexpr int TM = BM / WGM, TN = BN / WGN;
  constexpr int AM = TM / 32, AN = TN / 32;
  constexpr int LA = BM * BK / 2048, LB = BN * BK / 2048;
  __shared__ __align__(16) _Float16 As[BM * BK];
  __shared__ __align__(16) _Float16 Bs[BN * BK];
  const int tid = threadIdx.x;
  const int lane = tid & 63, w = tid >> 6;
  const int wr = (w / WGN) * TM, wc = (w % WGN) * TN;
  const int lr32 = lane & 31, half = lane >> 5;
  const int mb = blockIdx.y * BM, nb = blockIdx.x * BN;

  const _Float16* ga[LA];
  const _Float16* gb[LB];
  _Float16* la[LA];
  _Float16* lb[LB];
#pragma unroll
  for (int i = 0; i < LA; i++) {
    const int c = tid + i * 256, row = c / CPR, j = c % CPR;
    ga[i] = A + (size_t)(mb + row) * K + ((j ^ (row & 7)) << 3);
    la[i] = As + c * 8;
  }
#pragma unroll
  for (int i = 0; i < LB; i++) {
    const int c = tid + i * 256, row = c / CPR, j = c % CPR;
    gb[i] = Bt + (size_t)(nb + row) * K + ((j ^ (row & 7)) << 3);
    lb[i] = Bs + c * 8;
  }

  f32x16 acc[AM][AN] = {};

  for (int k0 = 0; k0 < K; k0 += BK) {
#pragma unroll
    for (int i = 0; i < LA; i++) gload16(ga[i] + k0, la[i]);
#pragma unroll
    for (int i = 0; i < LB; i++) gload16(gb[i] + k0, lb[i]);
    __syncthreads();
#pragma unroll
    for (int ks = 0; ks < BK / 16; ks++) {
      // lane's k-chunk for this step: logical chunk 2*ks+half, swizzled by row
      const int pc = (((ks << 1) | half) ^ (lr32 & 7)) << 3;
      half8 af[AM], bf[AN];
#pragma unroll
      for (int mt = 0; mt < AM; mt++)
        af[mt] = *(const half8*)(As + (wr + mt * 32 + lr32) * BK + pc);
#pragma unroll
      for (int nt = 0; nt < AN; nt++)
        bf[nt] = *(const half8*)(Bs + (wc + nt * 32 + lr32) * BK + pc);
#pragma unroll
      for (int mt = 0; mt < AM; mt++)
#pragma unroll
        for (int nt = 0; nt < AN; nt++)
          acc[mt][nt] = __builtin_amdgcn_mfma_f32_32x32x16_f16(af[mt], bf[nt], acc[mt][nt], 0, 0, 0);
    }
    __syncthreads();
  }

  float ls = 0.0f, lsq = 0.0f;
#pragma unroll
  for (int nt = 0; nt < AN; nt++) {
    const int col = nb + wc + (nt << 5) + lr32;
    const float bv = bias[col];
#pragma unroll
    for (int mt = 0; mt < AM; mt++) {
#pragma unroll
      for (int g = 0; g < 4; g++) {
        const int row0 = mb + wr + (mt << 5) + (g << 3) + (half << 2);
#pragma unroll
        for (int r = 0; r < 4; r++) {
          const int row = row0 + r;
          const size_t off = (size_t)row * N + col;
          float v = acc[mt][nt][(g << 2) + r] + bv;
          if (MODE == 0) {
            outH[off] = (_Float16)fmaxf(v, 0.0f);
          } else if (MODE == 1) {
            outH[off] = (_Float16)tanhf(v);
          } else if (MODE == 2) {
            outH[off] = (_Float16)v;
          } else if (MODE == 3) {
            outF[off] = v + aux[(size_t)(row & 511) * N + col];  // + pos_w[s]
          } else if (MODE == 4) {
            outH[off] = (_Float16)(0.5f * v * (1.0f + erff(v * 0.70710678118654752f)));
          } else if (MODE == 5) {
            float xv = aux[off] + v;  // residual add
            outF[off] = xv;
            outH[off] = (_Float16)xv;
          } else {
            outF[off] = v;
            if (MODE == 7) { ls += v; lsq += v * v; }
          }
        }
      }
    }
  }
  if (MODE == 7) {
#pragma unroll
    for (int o = 32; o; o >>= 1) { ls += __shfl_xor(ls, o); lsq += __shfl_xor(lsq, o); }
    if (lane == 0) {
      atomicAdd(&stats[0], ls);
      atomicAdd(&stats[1], lsq);
    }
  }
}

// ---------------------------------------------------------------------------
// LayerNorm over D=256; 4 rows/block. xn = fp16(LN(x))
__global__ __launch_bounds__(256) void ln_k(const float* __restrict__ x,
                                            const float* __restrict__ g,
                                            const float* __restrict__ b,
                                            _Float16* __restrict__ xn) {
  const int w = threadIdx.x >> 6, lane = threadIdx.x & 63;
  const int row = (blockIdx.x << 2) + w;
  const size_t base = ((size_t)row << 8) + (lane << 2);
  float4 v = *(const float4*)(x + base);
  float s = v.x + v.y + v.z + v.w;
  float sq = v.x * v.x + v.y * v.y + v.z * v.z + v.w * v.w;
#pragma unroll
  for (int o = 32; o; o >>= 1) { s += __shfl_xor(s, o); sq += __shfl_xor(sq, o); }
  const float mean = s * 0.00390625f;
  const float rs = rsqrtf(sq * 0.00390625f - mean * mean + 1e-5f);
  const int c = lane << 2;
  float4 gv = *(const float4*)(g + c);
  float4 bv = *(const float4*)(b + c);
  half4v o4;
  o4[0] = (_Float16)((v.x - mean) * rs * gv.x + bv.x);
  o4[1] = (_Float16)((v.y - mean) * rs * gv.y + bv.y);
  o4[2] = (_Float16)((v.z - mean) * rs * gv.z + bv.z);
  o4[3] = (_Float16)((v.w - mean) * rs * gv.w + bv.w);
  *(half4v*)(xn + base) = o4;
}

// x' = LN(x + a); writes x' fp32 and fp16 copy
__global__ __launch_bounds__(256) void add_ln_k(const float* __restrict__ x,
                                                const float* __restrict__ a,
                                                const float* __restrict__ g,
                                                const float* __restrict__ b,
                                                float* __restrict__ xo,
                                                _Float16* __restrict__ xn) {
  const int w = threadIdx.x >> 6, lane = threadIdx.x & 63;
  const int row = (blockIdx.x << 2) + w;
  const size_t base = ((size_t)row << 8) + (lane << 2);
  float4 v = *(const float4*)(x + base);
  float4 av = *(const float4*)(a + base);
  v.x += av.x; v.y += av.y; v.z += av.z; v.w += av.w;
  float s = v.x + v.y + v.z + v.w;
  float sq = v.x * v.x + v.y * v.y + v.z * v.z + v.w * v.w;
#pragma unroll
  for (int o = 32; o; o >>= 1) { s += __shfl_xor(s, o); sq += __shfl_xor(sq, o); }
  const float mean = s * 0.00390625f;
  const float rs = rsqrtf(sq * 0.00390625f - mean * mean + 1e-5f);
  const int c = lane << 2;
  float4 gv = *(const float4*)(g + c);
  float4 bv = *(const float4*)(b + c);
  float4 o4;
  o4.x = (v.x - mean) * rs * gv.x + bv.x;
  o4.y = (v.y - mean) * rs * gv.y + bv.y;
  o4.z = (v.z - mean) * rs * gv.z + bv.z;
  o4.w = (v.w - mean) * rs * gv.w + bv.w;
  *(float4*)(xo + base) = o4;
  half4v h;
  h[0] = (_Float16)o4.x; h[1] = (_Float16)o4.y; h[2] = (_Float16)o4.z; h[3] = (_Float16)o4.w;
  *(half4v*)(xn + base) = h;
}

// ---------------------------------------------------------------------------
// Causal flash attention. Block = (b, h, 64-row q-tile); 512 blocks.
#define HP0(v) ((half2v)__builtin_shufflevector((v), (v), 0, 1))
#define HP1(v) ((half2v)__builtin_shufflevector((v), (v), 2, 3))
#define HP2(v) ((half2v)__builtin_shufflevector((v), (v), 4, 5))
#define HP3(v) ((half2v)__builtin_shufflevector((v), (v), 6, 7))
__device__ __forceinline__ float dot8(half8 a, half8 b, float acc) {
  acc = __builtin_amdgcn_fdot2(HP0(a), HP0(b), acc, false);
  acc = __builtin_amdgcn_fdot2(HP1(a), HP1(b), acc, false);
  acc = __builtin_amdgcn_fdot2(HP2(a), HP2(b), acc, false);
  acc = __builtin_amdgcn_fdot2(HP3(a), HP3(b), acc, false);
  return acc;
}
__global__ __launch_bounds__(256) void attn_k(const _Float16* __restrict__ qkv,
                                              float* __restrict__ aout) {
  __shared__ __align__(16) char smem[65536];
  _Float16* Ks = (_Float16*)smem;
  _Float16* Vs = (_Float16*)(smem + 32768);
  float* Om = (float*)smem;
  float* Ol = (float*)(smem + 768);
  float* Os = (float*)(smem + 1536);

  const int bid = blockIdx.x;
  const int qt = 7 - (bid & 7), h = (bid >> 3) & 7, b = bid >> 6;
  const int q0 = qt << 6;
  const int t = threadIdx.x, p = t >> 6, tr = t & 63, q = q0 + tr;
  const int nkt = qt + 1;
  const size_t rowbase = (size_t)(b * 512) * 768;

  const half8* qr = (const half8*)(qkv + rowbase + (size_t)q * 768 + h * 32);
  half8 qf0 = qr[0], qf1 = qr[1], qf2 = qr[2], qf3 = qr[3];

  for (int c = t; c < nkt * 256; c += 256) {
    const int row = c >> 2, off = (c & 3) << 3;
    const _Float16* kp = qkv + rowbase + (size_t)row * 768 + 256 + h * 32 + off;
    gload16(kp, Ks + c * 8);
    gload16(kp + 256, Vs + c * 8);
  }
  __syncthreads();

  float O[32];
#pragma unroll
  for (int d = 0; d < 32; d++) O[d] = 0.0f;
  float m = -1e30f, lsum = 0.0f;

  for (int kt = p; kt < nkt; kt += 4) {
    const int kb = kt << 6;
    const int rows = (kt == qt) ? (tr + 1) : 64;
    for (int j0 = 0; j0 < rows; j0 += 8) {
      float s[8];
      float mx = -1e30f;
#pragma unroll
      for (int jj = 0; jj < 8; jj++) {
        const half8* kr = (const half8*)(Ks + (size_t)(kb + j0 + jj) * 32);
        float a0 = 0.0f, a1 = 0.0f, a2 = 0.0f, a3 = 0.0f;
        a0 = dot8(qf0, kr[0], a0);
        a1 = dot8(qf1, kr[1], a1);
        a2 = dot8(qf2, kr[2], a2);
        a3 = dot8(qf3, kr[3], a3);
        const float sc = ((a0 + a1) + (a2 + a3)) * 0.17677669529663687f;
        s[jj] = (kb + j0 + jj <= q) ? sc : -1e30f;
        mx = fmaxf(mx, s[jj]);
      }
      const float mn = fmaxf(m, mx);
      const float corr = __expf(m - mn);
      lsum *= corr;
#pragma unroll
      for (int d = 0; d < 32; d++) O[d] *= corr;
      m = mn;
#pragma unroll
      for (int jj = 0; jj < 8; jj++) {
        const float pw = __expf(s[jj] - m);
        lsum += pw;
        const half8* vr = (const half8*)(Vs + (size_t)(kb + j0 + jj) * 32);
#pragma unroll
        for (int i = 0; i < 4; i++) {
          half8 vv = vr[i];
#pragma unroll
          for (int d = 0; d < 8; d++) O[i * 8 + d] = fmaf(pw, (float)vv[d], O[i * 8 + d]);
        }
      }
    }
  }

  __syncthreads();
  if (p > 0) {
    Om[(p - 1) * 64 + tr] = m;
    Ol[(p - 1) * 64 + tr] = lsum;
    float* od = Os + ((p - 1) * 64 + tr) * 33;
#pragma unroll
    for (int d = 0; d < 32; d++) od[d] = O[d];
  }
  __syncthreads();
  if (p == 0) {
    float mn = m;
#pragma unroll
    for (int pp = 0; pp < 3; pp++) mn = fmaxf(mn, Om[pp * 64 + tr]);
    const float c0 = __expf(m - mn);
    float lt = lsum * c0;
    float cs[3];
#pragma unroll
    for (int pp = 0; pp < 3; pp++) {
      cs[pp] = __expf(Om[pp * 64 + tr] - mn);
      lt += Ol[pp * 64 + tr] * cs[pp];
    }
    const float inv = 1.0f / lt;
    float* op = aout + ((size_t)(b * 512 + q)) * 256 + h * 32;
#pragma unroll
    for (int d = 0; d < 32; d++) {
      float v = O[d] * c0;
#pragma unroll
      for (int pp = 0; pp < 3; pp++) v += Os[(pp * 64 + tr) * 33 + d] * cs[pp];
      op[d] = v * inv;
    }
  }
}

// ---------------------------------------------------------------------------
__global__ __launch_bounds__(256) void finalize_k(const float4* __restrict__ enc,
                                                  const float* __restrict__ stats,
                                                  float4* __restrict__ out, int n4, float n) {
  const int i = blockIdx.x * 256 + threadIdx.x;
  if (i >= n4) return;
  const float s = stats[0], q = stats[1];
  const float mean = s / n;
  const float var = (q - s * s / n) / (n - 1.0f);  // ddof=1
  const float inv = rsqrtf(var);
  float4 x = enc[i];
  float4 o;
  o.x = (x.x - mean) * inv + 1e-10f;
  o.y = (x.y - mean) * inv + 1e-10f;
  o.z = (x.z - mean) * inv + 1e-10f;
  o.w = (x.w - mean) * inv + 1e-10f;
  out[i] = o;
}

// ---------------------------------------------------------------------------
extern "C" void kernel_launch(void* const* d_in, const int* in_sizes, int n_in,
                              void* d_out, int out_size, void* d_ws, size_t ws_size,
                              hipStream_t stream) {
  const float* state = (const float*)d_in[0];
  const float* fc1_w = (const float*)d_in[1];
  const float* fc1_b = (const float*)d_in[2];
  const float* fc2_w = (const float*)d_in[3];
  const float* fc2_b = (const float*)d_in[4];
  const float* fc3_w = (const float*)d_in[5];
  const float* fc3_b = (const float*)d_in[6];
  const float* fc4_w = (const float*)d_in[7];
  const float* fc4_b = (const float*)d_in[8];
  const float* fc5_w = (const float*)d_in[9];
  const float* fc5_b = (const float*)d_in[10];
  const float* pre_w = (const float*)d_in[11];
  const float* pre_b = (const float*)d_in[12];
  const float* pos_w = (const float*)d_in[13];
  const float* enc_w = (const float*)d_in[14];
  const float* enc_b = (const float*)d_in[15];
  const float* ln1_g = (const float*)d_in[16];
  const float* ln1_b = (const float*)d_in[17];
  const float* ln2_g = (const float*)d_in[18];
  const float* ln2_b = (const float*)d_in[19];
  const float* res_w1 = (const float*)d_in[20];
  const float* res_b1 = (const float*)d_in[21];
  const float* res_w2 = (const float*)d_in[22];
  const float* res_b2 = (const float*)d_in[23];
  const float* out_w = (const float*)d_in[24];
  const float* out_b = (const float*)d_in[25];

  char* ws = (char*)d_ws;
  _Float16* wbuf = (_Float16*)ws;                       // 32 MiB
  _Float16* bufA16 = (_Float16*)(ws + (32 << 20));      // 32 MiB
  char* bufB = ws + (64 << 20);                         // 32 MiB

  // wbuf sub-allocs (half elements):
  _Float16* fc2T = wbuf;                 // [0,16Mi)
  _Float16* fc3T = wbuf + 8388608;       // [16,20Mi)
  _Float16* fc4T = wbuf + 10485760;      // [20,21Mi)
  _Float16* encT = wbuf + 11010048;      // [21,24Mi)
  _Float16* res1T = wbuf + 12582912;     // [24,28Mi)
  _Float16* res2T = wbuf + 14680064;     // [28,32Mi)
  // bufA tail (above all trunk/layer activations):
  _Float16* fc5T = bufA16 + 14680064;    // 28Mi
  _Float16* preT = bufA16 + 14811136;
  _Float16* outT = bufA16 + 14876672;
  // bufA activation sub-allocs:
  _Float16* xn16 = bufA16;               // 2 MiB
  _Float16* qkv16 = bufA16 + 1048576;    // 6 MiB
  _Float16* h16 = bufA16 + 4194304;      // 8 MiB
  _Float16* x16 = bufA16 + 8388608;      // 2 MiB
  // bufB sub-allocs (bytes):
  float* xres = (float*)(bufB + 8388608);    // 4 MiB
  float* aout = (float*)(bufB + 12582912);   // 4 MiB
  float* enc32 = (float*)(bufB + 20971520);  // 2 MiB
  float* stats = (float*)(bufB + 23068672);  // 8 B

  const dim3 tb(256);

  // ---- trunk ----
  cast_k<<<16384, tb, 0, stream>>>(state, bufA16, 16777216);
  t2_k<<<dim3(64, 128), tb, 0, stream>>>(fc1_w, wbuf, 4096, 4096);
  gemm_nt<128, 128, 64, 2, 2, 0><<<dim3(32, 32), tb, 0, stream>>>(bufA16, wbuf, fc1_b, (_Float16*)bufB, nullptr, nullptr, nullptr, 4096, 4096, 4096);
  tcast_comb<<<8304, tb, 0, stream>>>(fc2_w, fc2T, fc3_w, fc3T, fc4_w, fc4T, fc5_w, fc5T,
                                      pre_w, preT, enc_w, encT, res_w1, res1T, res_w2, res2T, out_w, outT);
  gemm_nt<128, 128, 64, 2, 2, 0><<<dim3(16, 32), tb, 0, stream>>>((_Float16*)bufB, fc2T, fc2_b, bufA16, nullptr, nullptr, nullptr, 4096, 2048, 4096);
  gemm_nt<128, 128, 64, 2, 2, 0><<<dim3(8, 32), tb, 0, stream>>>(bufA16, fc3T, fc3_b, (_Float16*)bufB, nullptr, nullptr, nullptr, 4096, 1024, 2048);
  gemm_nt<128, 64, 64, 4, 1, 0><<<dim3(8, 32), tb, 0, stream>>>((_Float16*)bufB, fc4T, fc4_b, bufA16, nullptr, nullptr, nullptr, 4096, 512, 1024);
  gemm_nt<64, 64, 64, 2, 2, 1><<<dim3(4, 64), tb, 0, stream>>>(bufA16, fc5T, fc5_b, (_Float16*)bufB, nullptr, nullptr, nullptr, 4096, 256, 512);
  gemm_nt<64, 64, 64, 2, 2, 3><<<dim3(4, 64), tb, 0, stream>>>((_Float16*)bufB, preT, pre_b, nullptr, xres, pos_w, nullptr, 4096, 256, 256);

  // ---- transformer blocks ----
  for (int l = 0; l < 8; l++) {
    ln_k<<<1024, tb, 0, stream>>>(xres, ln1_g + l * 256, ln1_b + l * 256, xn16);
    gemm_nt<128, 64, 64, 4, 1, 2><<<dim3(12, 32), tb, 0, stream>>>(xn16, encT + (size_t)l * 196608, enc_b + l * 768,
                                                                   qkv16, nullptr, nullptr, nullptr, 4096, 768, 256);
    attn_k<<<512, tb, 0, stream>>>(qkv16, aout);
    add_ln_k<<<1024, tb, 0, stream>>>(xres, aout, ln2_g + l * 256, ln2_b + l * 256, xres, xn16);
    gemm_nt<128, 128, 64, 2, 2, 4><<<dim3(8, 32), tb, 0, stream>>>(xn16, res1T + (size_t)l * 262144, res_b1 + l * 1024,
                                                                   h16, nullptr, nullptr, nullptr, 4096, 1024, 256);
    gemm_nt<64, 64, 64, 2, 2, 5><<<dim3(4, 64), tb, 0, stream>>>(h16, res2T + (size_t)l * 262144, res_b2 + l * 256,
                                                                 x16, xres, xres, nullptr, 4096, 256, 1024);
  }

  // ---- output projection (+inline stats) + standardization ----
  (void)hipMemsetAsync(stats, 0, 2 * sizeof(float), stream);
  gemm_nt<64, 64, 64, 2, 2, 7><<<dim3(2, 64), tb, 0, stream>>>(x16, outT, out_b, nullptr, enc32, nullptr, stats, 4096, 128, 256);
  finalize_k<<<512, tb, 0, stream>>>((const float4*)enc32, stats, (float4*)d_out, 131072, 524288.0f);
}